// Round 7
// baseline (389.348 us; speedup 1.0000x reference)
//
#include <hip/hip_runtime.h>
#include <hip/hip_bf16.h>
#include <stdint.h>

// 2-layer LSTM (H=64) fused over T=336, B=4096, + final linear->sigmoid.
// UNIFORM-WAVE dual-stream version: 8 waves (512 thr), 16 batches/block.
// Wave pair (P = w>>1) owns j-slice [16P,16P+16) of BOTH layers; sub = w&1
// splits the K-dim of every matvec (partial gate sums exchanged via LDS f32).
// Layer-pipelined: half-A = {L1-MFMA(i-2)  ||  L0-nonlin(i-1)}  barrier
//                  half-B = {L0-MFMA(i)    ||  L1-nonlin(i-2)}  barrier
// Every wave issues MFMA + trans in the SAME code block -> MFMA/trans overlap
// does not depend on wave->SIMD pairing (which R4/R6 showed we cannot control).
// Trans cut 10 -> 6.5/element via exact quad-reciprocal + paired cell-tanh rcp.

typedef __attribute__((ext_vector_type(8))) short s16x8;
typedef __attribute__((ext_vector_type(4))) float f32x4;

#define MFMA_BF16 __builtin_amdgcn_mfma_f32_16x16x32_bf16
#define LOG2E     1.4426950408889634f
#define TWO_LOG2E 2.8853900817779268f

static __device__ __forceinline__ short f2bf(float f) {
    uint32_t u = __builtin_bit_cast(uint32_t, f);
    u += 0x7fffu + ((u >> 16) & 1u);   // round-to-nearest-even
    return (short)(u >> 16);
}
static __device__ __forceinline__ float fexp2(float t){ return __builtin_amdgcn_exp2f(t); }
static __device__ __forceinline__ float frcpf(float t){ return __builtin_amdgcn_rcpf(t); }
static __device__ __forceinline__ float fclampf(float v, float lo, float hi){
    return fminf(fmaxf(v, lo), hi);
}

// ---- macros (SUBLIT is a literal 0/1 so all vector indices are compile-time) ----

#define STAGE(i)  do { if (tid < 256) {                                            \
        const float* xp_ = xrow + (size_t)(i) * 9;                                 \
        _Pragma("unroll") for (int d_ = 0; d_ < 9; ++d_)                           \
            xs[(xs_wr + d_) ^ xswzw] = f2bf(xp_[d_]); }                            \
        __syncthreads(); } while (0)

// L0 gates(i): reads h0(i-1) = H0[(i+1)&1], x(i)
#define MFMA_L0_S0(i) do {                                                         \
    const uint32_t* Hr_ = H0[((i) + 1) & 1];                                       \
    s16x8 bx_ = *(const s16x8*)&xs[((i) & 15) * 512 + xrd];                        \
    s16x8 bh_ = *(const s16x8*)&Hr_[hk0];                                          \
    _Pragma("unroll") for (int m_ = 0; m_ < 4; ++m_) acc0[m_] = MFMA_BF16(aA[m_], bx_, bias0[m_], 0,0,0); \
    _Pragma("unroll") for (int m_ = 0; m_ < 4; ++m_) acc0[m_] = MFMA_BF16(aB[m_], bh_, acc0[m_], 0,0,0);  \
    _Pragma("unroll") for (int t_ = 0; t_ < 4; ++t_) xb0[xbW + t_*64] = make_float2(acc0[t_][2], acc0[t_][3]); \
} while (0)

#define MFMA_L0_S1(i) do {                                                         \
    const uint32_t* Hr_ = H0[((i) + 1) & 1];                                       \
    s16x8 bh_ = *(const s16x8*)&Hr_[hk1];                                          \
    _Pragma("unroll") for (int m_ = 0; m_ < 4; ++m_) acc0[m_] = MFMA_BF16(aB[m_], bh_, zf, 0,0,0);        \
    _Pragma("unroll") for (int t_ = 0; t_ < 4; ++t_) xb0[xbW + t_*64] = make_float2(acc0[t_][0], acc0[t_][1]); \
} while (0)

// L1 gates(i-2) at half-A of iter i: reads h0(i-2) = H0[i&1] (sub0), h1(i-3) = H1 (sub1)
#define MFMA_L1_S0(i) do {                                                         \
    const uint32_t* Hr_ = H0[(i) & 1];                                             \
    s16x8 ba_ = *(const s16x8*)&Hr_[hk0];                                          \
    s16x8 bb_ = *(const s16x8*)&Hr_[hk1];                                          \
    _Pragma("unroll") for (int m_ = 0; m_ < 4; ++m_) acc1[m_] = MFMA_BF16(aC[m_], ba_, bias1[m_], 0,0,0); \
    _Pragma("unroll") for (int m_ = 0; m_ < 4; ++m_) acc1[m_] = MFMA_BF16(aD[m_], bb_, acc1[m_], 0,0,0);  \
    _Pragma("unroll") for (int t_ = 0; t_ < 4; ++t_) xb1[xbW + t_*64] = make_float2(acc1[t_][2], acc1[t_][3]); \
} while (0)

#define MFMA_L1_S1(i) do {                                                         \
    s16x8 ba_ = *(const s16x8*)&H1[hk0];                                           \
    s16x8 bb_ = *(const s16x8*)&H1[hk1];                                           \
    _Pragma("unroll") for (int m_ = 0; m_ < 4; ++m_) acc1[m_] = MFMA_BF16(aC[m_], ba_, zf, 0,0,0);        \
    _Pragma("unroll") for (int m_ = 0; m_ < 4; ++m_) acc1[m_] = MFMA_BF16(aD[m_], bb_, acc1[m_], 0,0,0);  \
    _Pragma("unroll") for (int t_ = 0; t_ < 4; ++t_) xb1[xbW + t_*64] = make_float2(acc1[t_][0], acc1[t_][1]); \
} while (0)

// nonlin on 2 elems (r = 2*SUBLIT, 2*SUBLIT+1); adds partner partials from xbp;
// quad-rcp for the 4 gates, paired rcp for the 2 cell-tanh's; writes bf16 pair.
#define NONLIN(SUBLIT, acc, ca, cb, Hdst, xbp, hoa, hob) do {                      \
    _Pragma("unroll") for (int t_ = 0; t_ < 4; ++t_) {                             \
        float2 pp_ = (xbp)[t_*64];                                                 \
        acc[t_][2*(SUBLIT)]   += pp_.x;                                            \
        acc[t_][2*(SUBLIT)+1] += pp_.y;                                            \
    }                                                                              \
    float eg0_, eg1_, og0_, og1_;                                                  \
    {   float t0_ = fclampf(acc[0][2*(SUBLIT)], -30.f, 30.f);                      \
        float t1_ = fclampf(acc[1][2*(SUBLIT)], -30.f, 30.f);                      \
        float t2_ = fclampf(acc[2][2*(SUBLIT)], -30.f, 30.f);                      \
        float t3_ = fclampf(acc[3][2*(SUBLIT)], -30.f, 30.f);                      \
        float d0_ = 1.f + fexp2(t0_), d1_ = 1.f + fexp2(t1_);                      \
        float d2_ = 1.f + fexp2(t2_), d3_ = 1.f + fexp2(t3_);                      \
        float p01_ = d0_ * d1_, p23_ = d2_ * d3_;                                  \
        float rr_  = frcpf(p01_ * p23_);                                           \
        float q01_ = rr_ * p23_, q23_ = rr_ * p01_;                                \
        float iv_ = q01_ * d1_, fv_ = q01_ * d0_;                                  \
        float gv_ = fmaf(-2.f, q23_ * d3_, 1.f), ov_ = q23_ * d2_;                 \
        ca = fmaf(fv_, ca, iv_ * gv_);                                             \
        eg0_ = fexp2(fclampf(ca * TWO_LOG2E, -28.f, 28.f)); og0_ = ov_; }          \
    {   float t0_ = fclampf(acc[0][2*(SUBLIT)+1], -30.f, 30.f);                    \
        float t1_ = fclampf(acc[1][2*(SUBLIT)+1], -30.f, 30.f);                    \
        float t2_ = fclampf(acc[2][2*(SUBLIT)+1], -30.f, 30.f);                    \
        float t3_ = fclampf(acc[3][2*(SUBLIT)+1], -30.f, 30.f);                    \
        float d0_ = 1.f + fexp2(t0_), d1_ = 1.f + fexp2(t1_);                      \
        float d2_ = 1.f + fexp2(t2_), d3_ = 1.f + fexp2(t3_);                      \
        float p01_ = d0_ * d1_, p23_ = d2_ * d3_;                                  \
        float rr_  = frcpf(p01_ * p23_);                                           \
        float q01_ = rr_ * p23_, q23_ = rr_ * p01_;                                \
        float iv_ = q01_ * d1_, fv_ = q01_ * d0_;                                  \
        float gv_ = fmaf(-2.f, q23_ * d3_, 1.f), ov_ = q23_ * d2_;                 \
        cb = fmaf(fv_, cb, iv_ * gv_);                                             \
        eg1_ = fexp2(fclampf(cb * TWO_LOG2E, -28.f, 28.f)); og1_ = ov_; }          \
    float dg0_ = 1.f + eg0_, dg1_ = 1.f + eg1_;                                    \
    float rg_  = frcpf(dg0_ * dg1_);                                               \
    float hva_ = og0_ * fmaf(-2.f, rg_ * dg1_, 1.f);                               \
    float hvb_ = og1_ * fmaf(-2.f, rg_ * dg0_, 1.f);                               \
    hoa = hva_; hob = hvb_;                                                        \
    uint32_t pk_;                                                                  \
    asm("v_cvt_pk_bf16_f32 %0, %1, %2" : "=v"(pk_) : "v"(hva_), "v"(hvb_));        \
    (Hdst)[hwr] = pk_;                                                             \
} while (0)

__global__ __launch_bounds__(512, 2)
void lstm_fused(const float* __restrict__ x,
                const float* __restrict__ w_ih0, const float* __restrict__ w_hh0,
                const float* __restrict__ b_ih0, const float* __restrict__ b_hh0,
                const float* __restrict__ w_ih1, const float* __restrict__ w_hh1,
                const float* __restrict__ b_ih1, const float* __restrict__ b_hh1,
                const float* __restrict__ w_lin, const float* __restrict__ b_lin,
                float* __restrict__ out)
{
    __shared__ __align__(16) short    xs[16 * 512];  // 16 KB bf16 x-chunk (K-padded)
    __shared__ __align__(16) uint32_t H0[2][512];    // 4 KB  h0 bf16-pairs, double buf
    __shared__ __align__(16) uint32_t H1[512];       // 2 KB  h1 bf16-pairs
    __shared__ __align__(16) float2   xb0[2048];     // 16 KB L0 gate-partial exchange
    __shared__ __align__(16) float2   xb1[2048];     // 16 KB L1 gate-partial exchange
    __shared__ float red[8][16];

    const int tid  = threadIdx.x;
    const int w    = tid >> 6;       // wave 0..7
    const int l    = tid & 63;
    const int bcol = l & 15;         // batch col
    const int q    = l >> 4;         // lane quad
    const int sub  = w & 1;          // K-split half
    const int P    = w >> 1;         // j-slice [16P,16P+16)
    const int b0   = blockIdx.x * 16;

    for (int i = tid; i < 16 * 512; i += 512) xs[i] = 0;
    if (tid < 512) { H0[0][tid] = 0; H0[1][tid] = 0; H1[tid] = 0; }
    __syncthreads();

    // sigma(x)=1/(1+2^(-x*log2e)); tanh(x)=1-2/(1+2^(2x*log2e)) — scales folded in.
    const float scm[4] = { -LOG2E, -LOG2E, TWO_LOG2E, -LOG2E };

    // A-frags (lane holds A[row=bcol][k=q*8+r]):
    // sub0: aA=W_ih0 (K 9->32 pad), aB=W_hh0[:,0:32),  aC=W_ih1[:,0:32), aD=W_ih1[:,32:64)
    // sub1: aA=unused,              aB=W_hh0[:,32:64), aC=W_hh1[:,0:32), aD=W_hh1[:,32:64)
    s16x8 aA[4], aB[4], aC[4], aD[4];
    f32x4 bias0[4], bias1[4];
    #pragma unroll
    for (int m = 0; m < 4; ++m) {
        const int R = m * 64 + P * 16 + bcol;
        const float sc = scm[m];
        if (sub == 0) {
            #pragma unroll
            for (int r = 0; r < 8; ++r) {
                int k = q * 8 + r;
                aA[m][r] = (k < 9) ? f2bf(w_ih0[R * 9 + k] * sc) : (short)0;
            }
            const float* pB = w_hh0 + R * 64 + q * 8;
            const float* pC = w_ih1 + R * 64 + q * 8;
            const float* pD = w_ih1 + R * 64 + 32 + q * 8;
            #pragma unroll
            for (int r = 0; r < 8; ++r) {
                aB[m][r] = f2bf(pB[r] * sc);
                aC[m][r] = f2bf(pC[r] * sc);
                aD[m][r] = f2bf(pD[r] * sc);
            }
        } else {
            const float* pB = w_hh0 + R * 64 + 32 + q * 8;
            const float* pC = w_hh1 + R * 64 + q * 8;
            const float* pD = w_hh1 + R * 64 + 32 + q * 8;
            #pragma unroll
            for (int r = 0; r < 8; ++r) {
                aA[m][r] = 0;
                aB[m][r] = f2bf(pB[r] * sc);
                aC[m][r] = f2bf(pC[r] * sc);
                aD[m][r] = f2bf(pD[r] * sc);
            }
        }
        #pragma unroll
        for (int r = 0; r < 4; ++r) {
            int G = m * 64 + P * 16 + q * 4 + r;
            bias0[m][r] = (b_ih0[G] + b_hh0[G]) * sc;
            bias1[m][r] = (b_ih1[G] + b_hh1[G]) * sc;
        }
    }

    // h storage: u32 H[b][p], p = j>>1, stored at p ^ ((b&7)<<2) (bank swizzle).
    const int hswz = (bcol & 7) << 2;
    const int hk0  = bcol * 32 + ((q * 4) ^ hswz);          // B-frag kf0 (4 consec u32)
    const int hk1  = bcol * 32 + ((16 + q * 4) ^ hswz);     // B-frag kf1
    const int hwr  = bcol * 32 + ((P * 8 + q * 2 + sub) ^ hswz);
    const int xrd  = bcol * 32 + ((q ^ (bcol & 3)) << 3);   // shorts
    const int xbW  = w * 256 + l;                           // own exchange rows (+t*64)
    const float2* xb0r = &xb0[(w ^ 1) * 256 + l];           // partner rows
    const float2* xb1r = &xb1[(w ^ 1) * 256 + l];

    const int    ld_b = tid >> 4, ld_t = tid & 15;          // staging (tid<256)
    const float* xrow = x + (size_t)(b0 + ld_b) * (336 * 9) + ld_t * 9;
    const int    xs_wr = ld_t * 512 + ld_b * 32;
    const int    xswzw = (ld_b & 3) << 3;

    f32x4 acc0[4], acc1[4];
    float c0a = 0.f, c0b = 0.f, c1a = 0.f, c1b = 0.f;
    float hfa = 0.f, hfb = 0.f, dmp0, dmp1;
    const f32x4 zf = {0.f, 0.f, 0.f, 0.f};

    // ---------------- pipeline head ----------------
    STAGE(0);
    __syncthreads();                                   // A(0): empty
    if (sub == 0) MFMA_L0_S0(0); else MFMA_L0_S1(0);   // B(0)
    __syncthreads();
    {                                                  // A(1): nonlin0(0) -> H0[0]
        uint32_t* Hw = H0[0];
        if (sub == 0) NONLIN(0, acc0, c0a, c0b, Hw, xb0r, dmp0, dmp1);
        else          NONLIN(1, acc0, c0a, c0b, Hw, xb0r, dmp0, dmp1);
    }
    __syncthreads();
    if (sub == 0) MFMA_L0_S0(1); else MFMA_L0_S1(1);   // B(1)
    __syncthreads();

    // ---------------- steady state ----------------
    #pragma unroll 1
    for (int i = 2; i <= 335; ++i) {
        if ((i & 15) == 0) STAGE(i);
        uint32_t* Hw0 = H0[(i & 1) ^ 1];               // h0(i-1) target
        // half A: L1-MFMA(i-2)  ||  L0-nonlin(i-1)
        if (sub == 0) { MFMA_L1_S0(i); NONLIN(0, acc0, c0a, c0b, Hw0, xb0r, dmp0, dmp1); }
        else          { MFMA_L1_S1(i); NONLIN(1, acc0, c0a, c0b, Hw0, xb0r, dmp0, dmp1); }
        __syncthreads();
        // half B: L0-MFMA(i)  ||  L1-nonlin(i-2)
        if (sub == 0) { MFMA_L0_S0(i); NONLIN(0, acc1, c1a, c1b, H1, xb1r, hfa, hfb); }
        else          { MFMA_L0_S1(i); NONLIN(1, acc1, c1a, c1b, H1, xb1r, hfa, hfb); }
        __syncthreads();
    }

    // ---------------- pipeline tail ----------------
    {   // i=336  A: L1-MFMA(334) + nonlin0(335) -> H0[1]
        uint32_t* Hw0 = H0[1];
        if (sub == 0) { MFMA_L1_S0(336); NONLIN(0, acc0, c0a, c0b, Hw0, xb0r, dmp0, dmp1); }
        else          { MFMA_L1_S1(336); NONLIN(1, acc0, c0a, c0b, Hw0, xb0r, dmp0, dmp1); }
        __syncthreads();
        //        B: nonlin1(334)
        if (sub == 0) NONLIN(0, acc1, c1a, c1b, H1, xb1r, hfa, hfb);
        else          NONLIN(1, acc1, c1a, c1b, H1, xb1r, hfa, hfb);
        __syncthreads();
    }
    {   // i=337  A: L1-MFMA(335)  (h0(335)=H0[1], h1(334)=H1)
        if (sub == 0) MFMA_L1_S0(337); else MFMA_L1_S1(337);
        __syncthreads();
        //        B: nonlin1(335) -> hfa/hfb = h1_final
        if (sub == 0) NONLIN(0, acc1, c1a, c1b, H1, xb1r, hfa, hfb);
        else          NONLIN(1, acc1, c1a, c1b, H1, xb1r, hfa, hfb);
    }

    // ---- out[b] = sigm(sum_j h1_335[b][j] * w_lin[j] + b_lin) ----
    {
        const int j0 = P * 16 + q * 4 + 2 * sub;
        float part = hfa * w_lin[j0] + hfb * w_lin[j0 + 1];
        part += __shfl_xor(part, 16, 64);
        part += __shfl_xor(part, 32, 64);
        if (q == 0) red[w][bcol] = part;
    }
    __syncthreads();
    if (tid < 16) {
        float s = b_lin[0];
        #pragma unroll
        for (int ww = 0; ww < 8; ++ww) s += red[ww][tid];
        out[b0 + tid] = frcpf(1.f + fexp2(-s * LOG2E));
    }
}

extern "C" void kernel_launch(void* const* d_in, const int* in_sizes, int n_in,
                              void* d_out, int out_size, void* d_ws, size_t ws_size,
                              hipStream_t stream) {
    const float* x     = (const float*)d_in[0];
    const float* w_ih0 = (const float*)d_in[1];
    const float* w_hh0 = (const float*)d_in[2];
    const float* b_ih0 = (const float*)d_in[3];
    const float* b_hh0 = (const float*)d_in[4];
    const float* w_ih1 = (const float*)d_in[5];
    const float* w_hh1 = (const float*)d_in[6];
    const float* b_ih1 = (const float*)d_in[7];
    const float* b_hh1 = (const float*)d_in[8];
    const float* w_lin = (const float*)d_in[9];
    const float* b_lin = (const float*)d_in[10];

    lstm_fused<<<dim3(256), dim3(512), 0, stream>>>(
        x, w_ih0, w_hh0, b_ih0, b_hh0,
        w_ih1, w_hh1, b_ih1, b_hh1,
        w_lin, b_lin, (float*)d_out);
}